// Round 22
// baseline (200.746 us; speedup 1.0000x reference)
//
#include <hip/hip_runtime.h>
#include <hip/hip_bf16.h>

// GTO_Atten pipeline V22, MI355X (gfx950).
// = V21 (best, 200.7us) + T5 s_setprio around attn1's MFMA clusters (m191-backed:
// multi-block/CU, phase-diverse waves). Everything else byte-identical to V21.

#define NB 4
#define NSEQ 8192
#define CD 512
#define NH 8
#define TD 64
#define NTOK 256
#define NSPLIT 16
#define NKEYS (NSEQ / NSPLIT)   // 512 keys per split
#define LOG2E 1.44269504f

typedef unsigned short u16;
typedef unsigned int u32;
typedef __bf16 bf16x8 __attribute__((ext_vector_type(8)));
typedef float f32x4 __attribute__((ext_vector_type(4)));
typedef float f32x16 __attribute__((ext_vector_type(16)));

__device__ __forceinline__ u16 f2bf(float f){
  __hip_bfloat16 h = __float2bfloat16(f);
  u16 u; __builtin_memcpy(&u, &h, 2); return u;
}
__device__ __forceinline__ bf16x8 ld8(const u16* p){
  bf16x8 r; __builtin_memcpy(&r, p, 16); return r;
}
__device__ __forceinline__ f32x4 mfma16(bf16x8 a, bf16x8 b, f32x4 c){
  return __builtin_amdgcn_mfma_f32_16x16x32_bf16(a, b, c, 0, 0, 0);
}
__device__ __forceinline__ f32x16 mfma32(bf16x8 a, bf16x8 b, f32x16 c){
  return __builtin_amdgcn_mfma_f32_32x32x16_bf16(a, b, c, 0, 0, 0);
}
__device__ __forceinline__ float fexp2(float x){
  return __builtin_amdgcn_exp2f(x);
}
__device__ __forceinline__ void gload16(const u16* g, u16* l){
  __builtin_amdgcn_global_load_lds((const __attribute__((address_space(1))) void*)g,
                                   (__attribute__((address_space(3))) void*)l, 16, 0, 0);
}

// ---------------- K0: cvt W0 + prep weights (merged; grid 16384) --------------------
__global__ void k_cvt_prep(const float* __restrict__ W0, u16* __restrict__ W0b,
                           const float* __restrict__ kv1_w, const float* __restrict__ q3_w,
                           const float* __restrict__ proj_w, const float* __restrict__ Q,
                           u16* __restrict__ kv1_wt, u16* __restrict__ q3_wt,
                           u16* __restrict__ proj_wt, u16* __restrict__ Qb){
  size_t i = (size_t)blockIdx.x * 256 + threadIdx.x;
  float4 v = ((const float4*)W0)[i];
  u16 w[4] = { f2bf(v.x), f2bf(v.y), f2bf(v.z), f2bf(v.w) };
  __builtin_memcpy(W0b + i*4, w, 8);
  if (i < (size_t)CD*CD){
    int k = (int)i >> 9, n = (int)i & 511;
    kv1_wt [n*CD + k] = f2bf(kv1_w[i]);
    q3_wt  [n*CD + k] = f2bf(q3_w[i] * (0.125f * LOG2E));
    proj_wt[n*CD + k] = f2bf(proj_w[i]);
    if (i < NH*NTOK*TD) Qb[i] = f2bf(Q[i] * (0.125f * LOG2E));
  }
}

// ---------------- Fused dual GEMM: gload_lds staging + rule-#21 swizzle (V20) -------
__global__ __launch_bounds__(256, 2)
void k_gemm_dual(const u16* __restrict__ A, const u16* __restrict__ B1t,
                 const u16* __restrict__ B2t, const float* __restrict__ bias1,
                 const float* __restrict__ bias2, float bscale2,
                 u16* __restrict__ out1, u16* __restrict__ out2){
  __shared__ __attribute__((aligned(16))) u16 smem[3 * 128 * 64];   // 49152 B
  u16* As  = smem;
  u16* B1s = smem + 128*64;
  u16* B2s = smem + 2*128*64;
  const int tid = threadIdx.x;
  const int lane = tid & 63, wave = tid >> 6;
  const int l15 = lane & 15, lg = lane >> 4;
  const int wm = (wave >> 1) * 64, wn = (wave & 1) * 64;
  const int bm = blockIdx.x, bn = blockIdx.y;
  const int lr = lane >> 3;
  const int csw = ((lane & 7) ^ lr) * 8;
  f32x4 acc1[4][4] = {}, acc2[4][4] = {};

#pragma unroll 1
  for (int k0 = 0; k0 < CD; k0 += 64){
    __syncthreads();
#pragma unroll
    for (int i = 0; i < 4; i++){
      int seg = i*4 + wave;
      int ch  = seg*8 + lr;
      gload16(A   + (size_t)(bm*128 + ch)*CD + k0 + csw, As  + seg*512);
      gload16(B1t + (size_t)(bn*128 + ch)*CD + k0 + csw, B1s + seg*512);
      gload16(B2t + (size_t)(bn*128 + ch)*CD + k0 + csw, B2s + seg*512);
    }
    __syncthreads();
#pragma unroll
    for (int ks = 0; ks < 2; ks++){
      bf16x8 af[4], b1f[4], b2f[4];
#pragma unroll
      for (int mf = 0; mf < 4; mf++){
        int R = wm + mf*16 + l15;
        int off = R*64 + (((ks*4 + lg) ^ (R & 7)) << 3);
        af[mf] = ld8(As + off);
      }
#pragma unroll
      for (int nf = 0; nf < 4; nf++){
        int R = wn + nf*16 + l15;
        int off = R*64 + (((ks*4 + lg) ^ (R & 7)) << 3);
        b1f[nf] = ld8(B1s + off);
        b2f[nf] = ld8(B2s + off);
      }
#pragma unroll
      for (int mf = 0; mf < 4; mf++)
#pragma unroll
        for (int nf = 0; nf < 4; nf++){
          acc1[mf][nf] = mfma16(af[mf], b1f[nf], acc1[mf][nf]);
          acc2[mf][nf] = mfma16(af[mf], b2f[nf], acc2[mf][nf]);
        }
    }
  }

  // ---- epilogue via LDS: cs overlays smem (34816 B < 49152) ----
  u16 (*cs)[136] = (u16 (*)[136])smem;
  const int erow = tid >> 1, ecol0 = (tid & 1) * 64;
  __syncthreads();
#pragma unroll
  for (int nf = 0; nf < 4; nf++){
    int col = wn + nf*16 + l15;
    float bv = bias1[bn*128 + col];
#pragma unroll
    for (int mf = 0; mf < 4; mf++){
      int row = wm + mf*16 + lg*4;
#pragma unroll
      for (int q = 0; q < 4; q++) cs[row + q][col] = f2bf(acc1[mf][nf][q] + bv);
    }
  }
  __syncthreads();
#pragma unroll
  for (int e = 0; e < 8; e++){
    int4 v; __builtin_memcpy(&v, &cs[erow][ecol0 + e*8], 16);
    __builtin_memcpy(out1 + (size_t)(bm*128 + erow)*CD + bn*128 + ecol0 + e*8, &v, 16);
  }
  __syncthreads();
#pragma unroll
  for (int nf = 0; nf < 4; nf++){
    int col = wn + nf*16 + l15;
    float bv = bias2[bn*128 + col] * bscale2;
#pragma unroll
    for (int mf = 0; mf < 4; mf++){
      int row = wm + mf*16 + lg*4;
#pragma unroll
      for (int q = 0; q < 4; q++) cs[row + q][col] = f2bf(acc2[mf][nf][q] + bv);
    }
  }
  __syncthreads();
#pragma unroll
  for (int e = 0; e < 8; e++){
    int4 v; __builtin_memcpy(&v, &cs[erow][ecol0 + e*8], 16);
    __builtin_memcpy(out2 + (size_t)(bm*128 + erow)*CD + bn*128 + ecol0 + e*8, &v, 16);
  }
}

// ---------------- GEMM (proj): gload_lds staging + rule-#21 swizzle (V21) -----------
__global__ __launch_bounds__(256, 2)
void k_gemm_proj(const u16* __restrict__ A, const u16* __restrict__ Bt,
                 const float* __restrict__ bias, float* __restrict__ outp){
  __shared__ __attribute__((aligned(16))) u16 smem[2 * 128 * 64];   // 32768 B
  u16* As = smem;
  u16* Bs = smem + 128*64;
  const int tid = threadIdx.x;
  const int lane = tid & 63, wave = tid >> 6;
  const int l15 = lane & 15, lg = lane >> 4;
  const int wm = (wave >> 1) * 64, wn = (wave & 1) * 64;
  const int bm = blockIdx.x, bn = blockIdx.y;
  const int lr = lane >> 3;
  const int csw = ((lane & 7) ^ lr) * 8;
  f32x4 acc[4][4] = {};

#pragma unroll 1
  for (int k0 = 0; k0 < CD; k0 += 64){
    __syncthreads();
#pragma unroll
    for (int i = 0; i < 4; i++){
      int seg = i*4 + wave;
      int ch  = seg*8 + lr;
      gload16(A  + (size_t)(bm*128 + ch)*CD + k0 + csw, As + seg*512);
      gload16(Bt + (size_t)(bn*128 + ch)*CD + k0 + csw, Bs + seg*512);
    }
    __syncthreads();
#pragma unroll
    for (int ks = 0; ks < 2; ks++){
      bf16x8 af[4], bfr[4];
#pragma unroll
      for (int mf = 0; mf < 4; mf++){
        int R = wm + mf*16 + l15;
        int off = R*64 + (((ks*4 + lg) ^ (R & 7)) << 3);
        af[mf] = ld8(As + off);
      }
#pragma unroll
      for (int nf = 0; nf < 4; nf++){
        int R = wn + nf*16 + l15;
        int off = R*64 + (((ks*4 + lg) ^ (R & 7)) << 3);
        bfr[nf] = ld8(Bs + off);
      }
#pragma unroll
      for (int mf = 0; mf < 4; mf++)
#pragma unroll
        for (int nf = 0; nf < 4; nf++)
          acc[mf][nf] = mfma16(af[mf], bfr[nf], acc[mf][nf]);
    }
  }
#pragma unroll
  for (int nf = 0; nf < 4; nf++){
    int col = bn*128 + wn + nf*16 + l15;
    float bv = bias[col];
#pragma unroll
    for (int mf = 0; mf < 4; mf++){
      int row = bm*128 + wm + mf*16 + lg*4;
#pragma unroll
      for (int q = 0; q < 4; q++)
        outp[(size_t)(row + q)*CD + col] = acc[mf][nf][q] + bv;
    }
  }
}

// ---------------- K2: attn1 — swapped-QK^T 32x32, fast-exp2, T5 setprio -------------
__global__ __launch_bounds__(256, 3)
void k_attn1(const u16* __restrict__ kv1, const u16* __restrict__ Qb,
             float* __restrict__ o_part, float* __restrict__ ml_part){
  __shared__ __attribute__((aligned(16))) u16 kvs[64][72];    // [key][td]
  __shared__ __attribute__((aligned(16))) u16 kvts[64][72];   // [td][key]
  const int tid = threadIdx.x, lane = tid & 63, wave = tid >> 6;
  const int bh = blockIdx.x, mt = blockIdx.y, s = blockIdx.z;
  const int b = bh >> 3, h = bh & 7;
  const int l31 = lane & 31, hi = lane >> 5;
  const int m0 = mt*128 + wave*32;

  bf16x8 bq[4];
#pragma unroll
  for (int ks = 0; ks < 4; ks++)
    bq[ks] = ld8(Qb + (size_t)(h*NTOK + m0 + l31)*TD + ks*16 + hi*8);

  float mrun = -1e30f, srun = 0.f;
  f32x16 o0 = {}, o1 = {};

#pragma unroll 1
  for (int c = 0; c < NKEYS/64; c++){
    const int nc = s*NKEYS + c*64;
    __syncthreads();
    {
      int r = tid >> 2, sg = tid & 3, seg = sg * 16;
      const u16* src = kv1 + (size_t)(b*NSEQ + nc + r)*CD + h*TD + seg;
      int4 v0 = *(const int4*)src;
      int4 v1 = *(const int4*)(src + 8);
      __builtin_memcpy(&kvs[r][seg],     &v0, 16);
      __builtin_memcpy(&kvs[r][seg + 8], &v1, 16);
      u32 tr[8];
      __builtin_memcpy(tr,     &v0, 16);
      __builtin_memcpy(tr + 4, &v1, 16);
      u32 t1[8], t2[8];
#pragma unroll
      for (int i = 0; i < 8; i++) t1[i] = (sg & 1) ? tr[(i + 1) & 7] : tr[i];
#pragma unroll
      for (int i = 0; i < 8; i++) t2[i] = (sg & 2) ? t1[(i + 2) & 7] : t1[i];
#pragma unroll
      for (int j2 = 0; j2 < 8; j2++){
        int jj = (2*j2 + 2*sg) & 15;
        kvts[seg + jj][r]     = (u16)(t2[j2] & 0xffff);
        kvts[seg + jj + 1][r] = (u16)(t2[j2] >> 16);
      }
    }
    __syncthreads();
#pragma unroll
    for (int sub = 0; sub < 2; sub++){
      f32x16 t = {};
      __builtin_amdgcn_s_setprio(1);
#pragma unroll
      for (int ks = 0; ks < 4; ks++){
        bf16x8 ak = ld8(&kvs[sub*32 + l31][ks*16 + hi*8]);
        t = mfma32(ak, bq[ks], t);
      }
      __builtin_amdgcn_s_setprio(0);
      float c0 = fmaxf(fmaxf(t[0], t[1]),  fmaxf(t[2], t[3]));
      float c1 = fmaxf(fmaxf(t[4], t[5]),  fmaxf(t[6], t[7]));
      float c2 = fmaxf(fmaxf(t[8], t[9]),  fmaxf(t[10], t[11]));
      float c3 = fmaxf(fmaxf(t[12], t[13]), fmaxf(t[14], t[15]));
      float cm = fmaxf(fmaxf(c0, c1), fmaxf(c2, c3));
      cm = fmaxf(cm, __shfl_xor(cm, 32, 64));
      if (!__all(cm <= mrun + 11.5416f)){
        float mnew = fmaxf(mrun, cm);
        float corr = fexp2(mrun - mnew);
        srun *= corr;
#pragma unroll
        for (int r = 0; r < 16; r++){ o0[r] *= corr; o1[r] *= corr; }
        mrun = mnew;
      }
      u32 w[8], x[8];
      float ls = 0.f;
#pragma unroll
      for (int j = 0; j < 8; j++){
        float e0 = fexp2(t[2*j]     - mrun);
        float e1 = fexp2(t[2*j + 1] - mrun);
        ls += e0 + e1;
        w[j] = (u32)f2bf(e0) | ((u32)f2bf(e1) << 16);
      }
      srun += ls;
#pragma unroll
      for (int j = 0; j < 8; j++) x[j] = __shfl_xor(w[j], 32, 64);
      __builtin_amdgcn_s_setprio(1);
#pragma unroll
      for (int c2i = 0; c2i < 2; c2i++){
        u32 arr[4];
        arr[0] = hi ? x[4*c2i + 2] : w[4*c2i + 0];
        arr[1] = hi ? x[4*c2i + 3] : w[4*c2i + 1];
        arr[2] = hi ? w[4*c2i + 2] : x[4*c2i + 0];
        arr[3] = hi ? w[4*c2i + 3] : x[4*c2i + 1];
        bf16x8 pb; __builtin_memcpy(&pb, arr, 16);
        bf16x8 av0 = ld8(&kvts[l31][sub*32 + c2i*16 + hi*8]);
        bf16x8 av1 = ld8(&kvts[l31 + 32][sub*32 + c2i*16 + hi*8]);
        o0 = mfma32(av0, pb, o0);
        o1 = mfma32(av1, pb, o1);
      }
      __builtin_amdgcn_s_setprio(0);
    }
  }
  float rs = srun + __shfl_xor(srun, 32, 64);

  const size_t pbase = (size_t)(bh*NSPLIT + s);
  float* qrow = o_part + (pbase*NTOK + m0 + l31)*TD;
#pragma unroll
  for (int g = 0; g < 4; g++){
    float4 v0 = make_float4(o0[4*g+0], o0[4*g+1], o0[4*g+2], o0[4*g+3]);
    *(float4*)(qrow + 8*g + 4*hi) = v0;
    float4 v1 = make_float4(o1[4*g+0], o1[4*g+1], o1[4*g+2], o1[4*g+3]);
    *(float4*)(qrow + 32 + 8*g + 4*hi) = v1;
  }
  if (hi == 0){
    ml_part[(pbase*2)*NTOK + m0 + l31]     = mrun;
    ml_part[(pbase*2 + 1)*NTOK + m0 + l31] = rs;
  }
}

// ---------------- K3: combine partials + kv2 GEMM (log2-domain merge) ---------------
__global__ __launch_bounds__(256, 2)
void k_comb(const float* __restrict__ o_part, const float* __restrict__ ml_part,
            const float* __restrict__ qkv2_w, u16* __restrict__ kb, u16* __restrict__ vtb){
  __shared__ float w2[TD*2*TD];       // 32KB
  __shared__ float osh[16][68];
  const int tid = threadIdx.x;
  const int bh = blockIdx.x >> 4, mtile = blockIdx.x & 15;
  const int m0 = mtile * 16;
  for (int i = tid; i < TD*2*TD/4; i += 256) ((float4*)w2)[i] = ((const float4*)qkv2_w)[i];

  const int mi = tid >> 4, tj = tid & 15;
  const int m = m0 + mi;
  float M = -1e30f;
#pragma unroll
  for (int s = 0; s < NSPLIT; s++)
    M = fmaxf(M, ml_part[(size_t)((bh*NSPLIT + s)*2)*NTOK + m]);
  float4 acc = make_float4(0.f,0.f,0.f,0.f);
  float denom = 0.f;
#pragma unroll 1
  for (int s = 0; s < NSPLIT; s++){
    size_t base = (size_t)(bh*NSPLIT + s);
    float w = fexp2(ml_part[(base*2)*NTOK + m] - M);
    denom += ml_part[(base*2 + 1)*NTOK + m] * w;
    float4 v = ((const float4*)(o_part + (base*NTOK + m)*TD))[tj];
    acc.x += w*v.x; acc.y += w*v.y; acc.z += w*v.z; acc.w += w*v.w;
  }
  float inv = 1.f / denom;
  osh[mi][tj*4+0] = acc.x*inv; osh[mi][tj*4+1] = acc.y*inv;
  osh[mi][tj*4+2] = acc.z*inv; osh[mi][tj*4+3] = acc.w*inv;
  __syncthreads();
  const int j0 = tj * 8;
  float o8[8] = {};
#pragma unroll
  for (int t = 0; t < TD; t++){
    float ov = osh[mi][t];
#pragma unroll
    for (int jj = 0; jj < 8; jj++) o8[jj] += ov * w2[t*2*TD + j0 + jj];
  }
  if (j0 < TD){
#pragma unroll
    for (int jj = 0; jj < 8; jj++)
      kb[(size_t)(bh*NTOK + m)*TD + j0 + jj] = f2bf(o8[jj]);
  } else {
#pragma unroll
    for (int jj = 0; jj < 8; jj++)
      vtb[(size_t)(bh*TD + (j0 - TD + jj))*NTOK + m] = f2bf(o8[jj]);
  }
}

// ---------------- K5: attn2 — swizzled LDS-staged K/V, fast-exp2 softmax ------------
__global__ __launch_bounds__(256, 2)
void k_attn2(const u16* __restrict__ q3, const u16* __restrict__ kb,
             const u16* __restrict__ vtb, u16* __restrict__ Wout){
  __shared__ __attribute__((aligned(16))) u16 buf[32768];   // 64KB exactly
  u16* kbs = buf;            // swizzled [256][64]: addr16 = r*64 + ((g ^ (r&7))<<3)
  u16* vts = buf + 16384;    // swizzled [64][256]: addr16 = t*256 + ((g ^ (t&31))<<3)
  const int tid = threadIdx.x, lane = tid & 63, wave = tid >> 6;
  const int bh = blockIdx.x >> 6, nt = blockIdx.x & 63;
  const int b = bh >> 3, h = bh & 7;
  const int l31 = lane & 31, hi = lane >> 5;
  const int n0 = nt * 128 + wave * 32;

  bf16x8 bq[4];
#pragma unroll
  for (int ks = 0; ks < 4; ks++)
    bq[ks] = ld8(q3 + (size_t)(b*NSEQ + n0 + l31)*CD + h*TD + ks*16 + hi*8);

  {
    const u16* ksrc = kb + (size_t)bh*NTOK*TD;
#pragma unroll
    for (int it = 0; it < 8; it++){
      int idx = it*256 + tid;
      int r = idx >> 3, g = idx & 7;
      int4 v; __builtin_memcpy(&v, ksrc + r*64 + g*8, 16);
      __builtin_memcpy(kbs + r*64 + ((g ^ (r & 7)) << 3), &v, 16);
    }
    const u16* vsrc = vtb + (size_t)bh*TD*NTOK;
#pragma unroll
    for (int it = 0; it < 8; it++){
      int idx = it*256 + tid;
      int t = idx >> 5, g = idx & 31;
      int4 v; __builtin_memcpy(&v, vsrc + t*256 + g*8, 16);
      __builtin_memcpy(vts + t*256 + ((g ^ (t & 31)) << 3), &v, 16);
    }
  }
  __syncthreads();

  f32x16 p[8] = {};
  __builtin_amdgcn_s_setprio(1);
#pragma unroll
  for (int kt = 0; kt < 8; kt++){
#pragma unroll
    for (int ks = 0; ks < 4; ks++){
      int r = kt*32 + l31, g = ks*2 + hi;
      bf16x8 ak = ld8(kbs + r*64 + ((g ^ (r & 7)) << 3));
      p[kt] = mfma32(ak, bq[ks], p[kt]);
    }
  }
  __builtin_amdgcn_s_setprio(0);

  float mx0 = -1e30f, mx1 = -1e30f, mx2 = -1e30f, mx3 = -1e30f;
#pragma unroll
  for (int kt = 0; kt < 8; kt++){
#pragma unroll
    for (int r = 0; r < 16; r += 4){
      mx0 = fmaxf(mx0, p[kt][r+0]); mx1 = fmaxf(mx1, p[kt][r+1]);
      mx2 = fmaxf(mx2, p[kt][r+2]); mx3 = fmaxf(mx3, p[kt][r+3]);
    }
  }
  float m = fmaxf(fmaxf(mx0, mx1), fmaxf(mx2, mx3));
  m = fmaxf(m, __shfl_xor(m, 32, 64));
  float s0 = 0.f, s1 = 0.f, s2 = 0.f, s3 = 0.f;
#pragma unroll
  for (int kt = 0; kt < 8; kt++){
#pragma unroll
    for (int r = 0; r < 16; r += 4){
      float e0 = fexp2(p[kt][r+0] - m); p[kt][r+0] = e0; s0 += e0;
      float e1 = fexp2(p[kt][r+1] - m); p[kt][r+1] = e1; s1 += e1;
      float e2 = fexp2(p[kt][r+2] - m); p[kt][r+2] = e2; s2 += e2;
      float e3 = fexp2(p[kt][r+3] - m); p[kt][r+3] = e3; s3 += e3;
    }
  }
  float rs = (s0 + s1) + (s2 + s3);
  rs += __shfl_xor(rs, 32, 64);
  const float inv = 1.f / rs;

  f32x16 o0 = {}, o1 = {};
#pragma unroll
  for (int kt = 0; kt < 8; kt++){
    u32 w[8], x[8];
#pragma unroll
    for (int j = 0; j < 8; j++){
      u32 lo = f2bf(p[kt][2*j]);
      u32 hh = f2bf(p[kt][2*j + 1]);
      w[j] = lo | (hh << 16);
    }
#pragma unroll
    for (int j = 0; j < 8; j++) x[j] = __shfl_xor(w[j], 32, 64);
    __builtin_amdgcn_s_setprio(1);
#pragma unroll
    for (int c = 0; c < 2; c++){
      u32 arr[4];
      arr[0] = hi ? x[4*c + 2] : w[4*c + 0];
      arr[1] = hi ? x[4*c + 3] : w[4*c + 1];
      arr[2] = hi ? w[4*c + 2] : x[4*c + 0];
      arr[3] = hi ? w[4*c + 3] : x[4*c + 1];
      bf16x8 pb; __builtin_memcpy(&pb, arr, 16);
      int g = kt*4 + c*2 + hi;
      bf16x8 av0 = ld8(vts + l31*256        + ((g ^ l31) << 3));
      bf16x8 av1 = ld8(vts + (l31+32)*256   + ((g ^ l31) << 3));
      o0 = mfma32(av0, pb, o0);
      o1 = mfma32(av1, pb, o1);
    }
    __builtin_amdgcn_s_setprio(0);
  }

  __syncthreads();
  u16 (*osh)[32][68] = (u16 (*)[32][68])buf;   // 4 x 32 x 68 = 17408 B
#pragma unroll
  for (int r = 0; r < 16; r++){
    int row = (r & 3) + 8*(r >> 2) + 4*hi;   // td within 32-block
    osh[wave][l31][row]      = f2bf(o0[r] * inv);
    osh[wave][l31][32 + row] = f2bf(o1[r] * inv);
  }
  const u16* src = &osh[wave][l31][hi*32];
  int4 v0, v1, v2, v3;
  __builtin_memcpy(&v0, src,      16);
  __builtin_memcpy(&v1, src + 8,  16);
  __builtin_memcpy(&v2, src + 16, 16);
  __builtin_memcpy(&v3, src + 24, 16);
  u16* dst = Wout + (size_t)(b*NSEQ + n0 + l31)*CD + h*TD + hi*32;
  __builtin_memcpy(dst,      &v0, 16);
  __builtin_memcpy(dst + 8,  &v1, 16);
  __builtin_memcpy(dst + 16, &v2, 16);
  __builtin_memcpy(dst + 24, &v3, 16);
}

// ---------------- host ----------------
extern "C" void kernel_launch(void* const* d_in, const int* in_sizes, int n_in,
                              void* d_out, int out_size, void* d_ws, size_t ws_size,
                              hipStream_t stream){
  const float* W0     = (const float*)d_in[0];
  const float* Q      = (const float*)d_in[1];
  const float* kv1_w  = (const float*)d_in[2];
  const float* kv1_b  = (const float*)d_in[3];
  const float* qkv2_w = (const float*)d_in[4];
  const float* q3_w   = (const float*)d_in[5];
  const float* q3_b   = (const float*)d_in[6];
  const float* proj_w = (const float*)d_in[7];
  const float* proj_b = (const float*)d_in[8];
  (void)in_sizes; (void)n_in; (void)out_size; (void)ws_size;

  char* ws = (char*)d_ws;
  u16*   W0b     = (u16*)  (ws);                                  // [0,32MiB)
  u16*   kv1_ws  = (u16*)  (ws + ((size_t)32<<20));               // [32,64) -> later W_ws
  float* o_part  = (float*)(ws + ((size_t)64<<20));               // [64,96)
  float* ml_part = (float*)(ws + ((size_t)96<<20));               // [96,97)
  u16*   kv1_wt  = (u16*)  (ws + ((size_t)97<<20));               // 512 KiB
  u16*   q3_wt   = (u16*)  (ws + ((size_t)97<<20) + (1<<19));     // 512 KiB
  u16*   proj_wt = (u16*)  (ws + ((size_t)98<<20));               // 512 KiB
  u16*   Qb      = (u16*)  (ws + ((size_t)98<<20) + (1<<19));     // 256 KiB
  u16*   kb      = (u16*)  (ws + ((size_t)99<<20));               // 1 MiB
  u16*   vtb     = (u16*)  (ws + ((size_t)100<<20));              // 1 MiB; total ~101 MiB
  u16*   W_ws    = (u16*)  (ws + ((size_t)32<<20));               // alias kv1_ws
  u16*   q3s     = (u16*)  d_out;                                 // first 32MB of d_out (64MB f32)

  k_cvt_prep<<<16384, 256, 0, stream>>>(W0, W0b, kv1_w, q3_w, proj_w, Q,
                                        kv1_wt, q3_wt, proj_wt, Qb);
  k_gemm_dual<<<dim3(256,4), 256, 0, stream>>>(W0b, kv1_wt, q3_wt, kv1_b, q3_b,
                                               0.125f * LOG2E, kv1_ws, q3s);
  k_attn1<<<dim3(NB*NH, 2, NSPLIT), 256, 0, stream>>>(kv1_ws, Qb, o_part, ml_part);
  k_comb<<<NB*NH*16, 256, 0, stream>>>(o_part, ml_part, qkv2_w, kb, vtb);
  k_attn2<<<NB*NH*64, 256, 0, stream>>>(q3s, kb, vtb, W_ws);
  k_gemm_proj<<<dim3(256,4), 256, 0, stream>>>(W_ws, proj_wt, proj_b, (float*)d_out);
}

// Round 23
// 199.899 us; speedup vs baseline: 1.0042x; 1.0042x over previous
//
#include <hip/hip_runtime.h>
#include <hip/hip_bf16.h>

// GTO_Atten pipeline V23, MI355X (gfx950).
// = V22 (200.7us) + attn1 __launch_bounds__(256,4) (16 waves/CU cap; VGPR fits
// ~125 < 128). Spill tripwire: attn1 WRITE_SIZE. All else byte-identical.

#define NB 4
#define NSEQ 8192
#define CD 512
#define NH 8
#define TD 64
#define NTOK 256
#define NSPLIT 16
#define NKEYS (NSEQ / NSPLIT)   // 512 keys per split
#define LOG2E 1.44269504f

typedef unsigned short u16;
typedef unsigned int u32;
typedef __bf16 bf16x8 __attribute__((ext_vector_type(8)));
typedef float f32x4 __attribute__((ext_vector_type(4)));
typedef float f32x16 __attribute__((ext_vector_type(16)));

__device__ __forceinline__ u16 f2bf(float f){
  __hip_bfloat16 h = __float2bfloat16(f);
  u16 u; __builtin_memcpy(&u, &h, 2); return u;
}
__device__ __forceinline__ bf16x8 ld8(const u16* p){
  bf16x8 r; __builtin_memcpy(&r, p, 16); return r;
}
__device__ __forceinline__ f32x4 mfma16(bf16x8 a, bf16x8 b, f32x4 c){
  return __builtin_amdgcn_mfma_f32_16x16x32_bf16(a, b, c, 0, 0, 0);
}
__device__ __forceinline__ f32x16 mfma32(bf16x8 a, bf16x8 b, f32x16 c){
  return __builtin_amdgcn_mfma_f32_32x32x16_bf16(a, b, c, 0, 0, 0);
}
__device__ __forceinline__ float fexp2(float x){
  return __builtin_amdgcn_exp2f(x);
}
__device__ __forceinline__ void gload16(const u16* g, u16* l){
  __builtin_amdgcn_global_load_lds((const __attribute__((address_space(1))) void*)g,
                                   (__attribute__((address_space(3))) void*)l, 16, 0, 0);
}

// ---------------- K0: cvt W0 + prep weights (merged; grid 16384) --------------------
__global__ void k_cvt_prep(const float* __restrict__ W0, u16* __restrict__ W0b,
                           const float* __restrict__ kv1_w, const float* __restrict__ q3_w,
                           const float* __restrict__ proj_w, const float* __restrict__ Q,
                           u16* __restrict__ kv1_wt, u16* __restrict__ q3_wt,
                           u16* __restrict__ proj_wt, u16* __restrict__ Qb){
  size_t i = (size_t)blockIdx.x * 256 + threadIdx.x;
  float4 v = ((const float4*)W0)[i];
  u16 w[4] = { f2bf(v.x), f2bf(v.y), f2bf(v.z), f2bf(v.w) };
  __builtin_memcpy(W0b + i*4, w, 8);
  if (i < (size_t)CD*CD){
    int k = (int)i >> 9, n = (int)i & 511;
    kv1_wt [n*CD + k] = f2bf(kv1_w[i]);
    q3_wt  [n*CD + k] = f2bf(q3_w[i] * (0.125f * LOG2E));
    proj_wt[n*CD + k] = f2bf(proj_w[i]);
    if (i < NH*NTOK*TD) Qb[i] = f2bf(Q[i] * (0.125f * LOG2E));
  }
}

// ---------------- Fused dual GEMM: gload_lds staging + rule-#21 swizzle (V20) -------
__global__ __launch_bounds__(256, 2)
void k_gemm_dual(const u16* __restrict__ A, const u16* __restrict__ B1t,
                 const u16* __restrict__ B2t, const float* __restrict__ bias1,
                 const float* __restrict__ bias2, float bscale2,
                 u16* __restrict__ out1, u16* __restrict__ out2){
  __shared__ __attribute__((aligned(16))) u16 smem[3 * 128 * 64];   // 49152 B
  u16* As  = smem;
  u16* B1s = smem + 128*64;
  u16* B2s = smem + 2*128*64;
  const int tid = threadIdx.x;
  const int lane = tid & 63, wave = tid >> 6;
  const int l15 = lane & 15, lg = lane >> 4;
  const int wm = (wave >> 1) * 64, wn = (wave & 1) * 64;
  const int bm = blockIdx.x, bn = blockIdx.y;
  const int lr = lane >> 3;
  const int csw = ((lane & 7) ^ lr) * 8;
  f32x4 acc1[4][4] = {}, acc2[4][4] = {};

#pragma unroll 1
  for (int k0 = 0; k0 < CD; k0 += 64){
    __syncthreads();
#pragma unroll
    for (int i = 0; i < 4; i++){
      int seg = i*4 + wave;
      int ch  = seg*8 + lr;
      gload16(A   + (size_t)(bm*128 + ch)*CD + k0 + csw, As  + seg*512);
      gload16(B1t + (size_t)(bn*128 + ch)*CD + k0 + csw, B1s + seg*512);
      gload16(B2t + (size_t)(bn*128 + ch)*CD + k0 + csw, B2s + seg*512);
    }
    __syncthreads();
#pragma unroll
    for (int ks = 0; ks < 2; ks++){
      bf16x8 af[4], b1f[4], b2f[4];
#pragma unroll
      for (int mf = 0; mf < 4; mf++){
        int R = wm + mf*16 + l15;
        int off = R*64 + (((ks*4 + lg) ^ (R & 7)) << 3);
        af[mf] = ld8(As + off);
      }
#pragma unroll
      for (int nf = 0; nf < 4; nf++){
        int R = wn + nf*16 + l15;
        int off = R*64 + (((ks*4 + lg) ^ (R & 7)) << 3);
        b1f[nf] = ld8(B1s + off);
        b2f[nf] = ld8(B2s + off);
      }
#pragma unroll
      for (int mf = 0; mf < 4; mf++)
#pragma unroll
        for (int nf = 0; nf < 4; nf++){
          acc1[mf][nf] = mfma16(af[mf], b1f[nf], acc1[mf][nf]);
          acc2[mf][nf] = mfma16(af[mf], b2f[nf], acc2[mf][nf]);
        }
    }
  }

  // ---- epilogue via LDS: cs overlays smem (34816 B < 49152) ----
  u16 (*cs)[136] = (u16 (*)[136])smem;
  const int erow = tid >> 1, ecol0 = (tid & 1) * 64;
  __syncthreads();
#pragma unroll
  for (int nf = 0; nf < 4; nf++){
    int col = wn + nf*16 + l15;
    float bv = bias1[bn*128 + col];
#pragma unroll
    for (int mf = 0; mf < 4; mf++){
      int row = wm + mf*16 + lg*4;
#pragma unroll
      for (int q = 0; q < 4; q++) cs[row + q][col] = f2bf(acc1[mf][nf][q] + bv);
    }
  }
  __syncthreads();
#pragma unroll
  for (int e = 0; e < 8; e++){
    int4 v; __builtin_memcpy(&v, &cs[erow][ecol0 + e*8], 16);
    __builtin_memcpy(out1 + (size_t)(bm*128 + erow)*CD + bn*128 + ecol0 + e*8, &v, 16);
  }
  __syncthreads();
#pragma unroll
  for (int nf = 0; nf < 4; nf++){
    int col = wn + nf*16 + l15;
    float bv = bias2[bn*128 + col] * bscale2;
#pragma unroll
    for (int mf = 0; mf < 4; mf++){
      int row = wm + mf*16 + lg*4;
#pragma unroll
      for (int q = 0; q < 4; q++) cs[row + q][col] = f2bf(acc2[mf][nf][q] + bv);
    }
  }
  __syncthreads();
#pragma unroll
  for (int e = 0; e < 8; e++){
    int4 v; __builtin_memcpy(&v, &cs[erow][ecol0 + e*8], 16);
    __builtin_memcpy(out2 + (size_t)(bm*128 + erow)*CD + bn*128 + ecol0 + e*8, &v, 16);
  }
}

// ---------------- GEMM (proj): gload_lds staging + rule-#21 swizzle (V21) -----------
__global__ __launch_bounds__(256, 2)
void k_gemm_proj(const u16* __restrict__ A, const u16* __restrict__ Bt,
                 const float* __restrict__ bias, float* __restrict__ outp){
  __shared__ __attribute__((aligned(16))) u16 smem[2 * 128 * 64];   // 32768 B
  u16* As = smem;
  u16* Bs = smem + 128*64;
  const int tid = threadIdx.x;
  const int lane = tid & 63, wave = tid >> 6;
  const int l15 = lane & 15, lg = lane >> 4;
  const int wm = (wave >> 1) * 64, wn = (wave & 1) * 64;
  const int bm = blockIdx.x, bn = blockIdx.y;
  const int lr = lane >> 3;
  const int csw = ((lane & 7) ^ lr) * 8;
  f32x4 acc[4][4] = {};

#pragma unroll 1
  for (int k0 = 0; k0 < CD; k0 += 64){
    __syncthreads();
#pragma unroll
    for (int i = 0; i < 4; i++){
      int seg = i*4 + wave;
      int ch  = seg*8 + lr;
      gload16(A  + (size_t)(bm*128 + ch)*CD + k0 + csw, As + seg*512);
      gload16(Bt + (size_t)(bn*128 + ch)*CD + k0 + csw, Bs + seg*512);
    }
    __syncthreads();
#pragma unroll
    for (int ks = 0; ks < 2; ks++){
      bf16x8 af[4], bfr[4];
#pragma unroll
      for (int mf = 0; mf < 4; mf++){
        int R = wm + mf*16 + l15;
        int off = R*64 + (((ks*4 + lg) ^ (R & 7)) << 3);
        af[mf] = ld8(As + off);
      }
#pragma unroll
      for (int nf = 0; nf < 4; nf++){
        int R = wn + nf*16 + l15;
        int off = R*64 + (((ks*4 + lg) ^ (R & 7)) << 3);
        bfr[nf] = ld8(Bs + off);
      }
#pragma unroll
      for (int mf = 0; mf < 4; mf++)
#pragma unroll
        for (int nf = 0; nf < 4; nf++)
          acc[mf][nf] = mfma16(af[mf], bfr[nf], acc[mf][nf]);
    }
  }
#pragma unroll
  for (int nf = 0; nf < 4; nf++){
    int col = bn*128 + wn + nf*16 + l15;
    float bv = bias[col];
#pragma unroll
    for (int mf = 0; mf < 4; mf++){
      int row = bm*128 + wm + mf*16 + lg*4;
#pragma unroll
      for (int q = 0; q < 4; q++)
        outp[(size_t)(row + q)*CD + col] = acc[mf][nf][q] + bv;
    }
  }
}

// ---------------- K2: attn1 — swapped-QK^T 32x32, fast-exp2; 4 waves/SIMD -----------
__global__ __launch_bounds__(256, 4)
void k_attn1(const u16* __restrict__ kv1, const u16* __restrict__ Qb,
             float* __restrict__ o_part, float* __restrict__ ml_part){
  __shared__ __attribute__((aligned(16))) u16 kvs[64][72];    // [key][td]
  __shared__ __attribute__((aligned(16))) u16 kvts[64][72];   // [td][key]
  const int tid = threadIdx.x, lane = tid & 63, wave = tid >> 6;
  const int bh = blockIdx.x, mt = blockIdx.y, s = blockIdx.z;
  const int b = bh >> 3, h = bh & 7;
  const int l31 = lane & 31, hi = lane >> 5;
  const int m0 = mt*128 + wave*32;

  bf16x8 bq[4];
#pragma unroll
  for (int ks = 0; ks < 4; ks++)
    bq[ks] = ld8(Qb + (size_t)(h*NTOK + m0 + l31)*TD + ks*16 + hi*8);

  float mrun = -1e30f, srun = 0.f;
  f32x16 o0 = {}, o1 = {};

#pragma unroll 1
  for (int c = 0; c < NKEYS/64; c++){
    const int nc = s*NKEYS + c*64;
    __syncthreads();
    {
      int r = tid >> 2, sg = tid & 3, seg = sg * 16;
      const u16* src = kv1 + (size_t)(b*NSEQ + nc + r)*CD + h*TD + seg;
      int4 v0 = *(const int4*)src;
      int4 v1 = *(const int4*)(src + 8);
      __builtin_memcpy(&kvs[r][seg],     &v0, 16);
      __builtin_memcpy(&kvs[r][seg + 8], &v1, 16);
      u32 tr[8];
      __builtin_memcpy(tr,     &v0, 16);
      __builtin_memcpy(tr + 4, &v1, 16);
      u32 t1[8], t2[8];
#pragma unroll
      for (int i = 0; i < 8; i++) t1[i] = (sg & 1) ? tr[(i + 1) & 7] : tr[i];
#pragma unroll
      for (int i = 0; i < 8; i++) t2[i] = (sg & 2) ? t1[(i + 2) & 7] : t1[i];
#pragma unroll
      for (int j2 = 0; j2 < 8; j2++){
        int jj = (2*j2 + 2*sg) & 15;
        kvts[seg + jj][r]     = (u16)(t2[j2] & 0xffff);
        kvts[seg + jj + 1][r] = (u16)(t2[j2] >> 16);
      }
    }
    __syncthreads();
#pragma unroll
    for (int sub = 0; sub < 2; sub++){
      f32x16 t = {};
      __builtin_amdgcn_s_setprio(1);
#pragma unroll
      for (int ks = 0; ks < 4; ks++){
        bf16x8 ak = ld8(&kvs[sub*32 + l31][ks*16 + hi*8]);
        t = mfma32(ak, bq[ks], t);
      }
      __builtin_amdgcn_s_setprio(0);
      float c0 = fmaxf(fmaxf(t[0], t[1]),  fmaxf(t[2], t[3]));
      float c1 = fmaxf(fmaxf(t[4], t[5]),  fmaxf(t[6], t[7]));
      float c2 = fmaxf(fmaxf(t[8], t[9]),  fmaxf(t[10], t[11]));
      float c3 = fmaxf(fmaxf(t[12], t[13]), fmaxf(t[14], t[15]));
      float cm = fmaxf(fmaxf(c0, c1), fmaxf(c2, c3));
      cm = fmaxf(cm, __shfl_xor(cm, 32, 64));
      if (!__all(cm <= mrun + 11.5416f)){
        float mnew = fmaxf(mrun, cm);
        float corr = fexp2(mrun - mnew);
        srun *= corr;
#pragma unroll
        for (int r = 0; r < 16; r++){ o0[r] *= corr; o1[r] *= corr; }
        mrun = mnew;
      }
      u32 w[8], x[8];
      float ls = 0.f;
#pragma unroll
      for (int j = 0; j < 8; j++){
        float e0 = fexp2(t[2*j]     - mrun);
        float e1 = fexp2(t[2*j + 1] - mrun);
        ls += e0 + e1;
        w[j] = (u32)f2bf(e0) | ((u32)f2bf(e1) << 16);
      }
      srun += ls;
#pragma unroll
      for (int j = 0; j < 8; j++) x[j] = __shfl_xor(w[j], 32, 64);
      __builtin_amdgcn_s_setprio(1);
#pragma unroll
      for (int c2i = 0; c2i < 2; c2i++){
        u32 arr[4];
        arr[0] = hi ? x[4*c2i + 2] : w[4*c2i + 0];
        arr[1] = hi ? x[4*c2i + 3] : w[4*c2i + 1];
        arr[2] = hi ? w[4*c2i + 2] : x[4*c2i + 0];
        arr[3] = hi ? w[4*c2i + 3] : x[4*c2i + 1];
        bf16x8 pb; __builtin_memcpy(&pb, arr, 16);
        bf16x8 av0 = ld8(&kvts[l31][sub*32 + c2i*16 + hi*8]);
        bf16x8 av1 = ld8(&kvts[l31 + 32][sub*32 + c2i*16 + hi*8]);
        o0 = mfma32(av0, pb, o0);
        o1 = mfma32(av1, pb, o1);
      }
      __builtin_amdgcn_s_setprio(0);
    }
  }
  float rs = srun + __shfl_xor(srun, 32, 64);

  const size_t pbase = (size_t)(bh*NSPLIT + s);
  float* qrow = o_part + (pbase*NTOK + m0 + l31)*TD;
#pragma unroll
  for (int g = 0; g < 4; g++){
    float4 v0 = make_float4(o0[4*g+0], o0[4*g+1], o0[4*g+2], o0[4*g+3]);
    *(float4*)(qrow + 8*g + 4*hi) = v0;
    float4 v1 = make_float4(o1[4*g+0], o1[4*g+1], o1[4*g+2], o1[4*g+3]);
    *(float4*)(qrow + 32 + 8*g + 4*hi) = v1;
  }
  if (hi == 0){
    ml_part[(pbase*2)*NTOK + m0 + l31]     = mrun;
    ml_part[(pbase*2 + 1)*NTOK + m0 + l31] = rs;
  }
}

// ---------------- K3: combine partials + kv2 GEMM (log2-domain merge) ---------------
__global__ __launch_bounds__(256, 2)
void k_comb(const float* __restrict__ o_part, const float* __restrict__ ml_part,
            const float* __restrict__ qkv2_w, u16* __restrict__ kb, u16* __restrict__ vtb){
  __shared__ float w2[TD*2*TD];       // 32KB
  __shared__ float osh[16][68];
  const int tid = threadIdx.x;
  const int bh = blockIdx.x >> 4, mtile = blockIdx.x & 15;
  const int m0 = mtile * 16;
  for (int i = tid; i < TD*2*TD/4; i += 256) ((float4*)w2)[i] = ((const float4*)qkv2_w)[i];

  const int mi = tid >> 4, tj = tid & 15;
  const int m = m0 + mi;
  float M = -1e30f;
#pragma unroll
  for (int s = 0; s < NSPLIT; s++)
    M = fmaxf(M, ml_part[(size_t)((bh*NSPLIT + s)*2)*NTOK + m]);
  float4 acc = make_float4(0.f,0.f,0.f,0.f);
  float denom = 0.f;
#pragma unroll 1
  for (int s = 0; s < NSPLIT; s++){
    size_t base = (size_t)(bh*NSPLIT + s);
    float w = fexp2(ml_part[(base*2)*NTOK + m] - M);
    denom += ml_part[(base*2 + 1)*NTOK + m] * w;
    float4 v = ((const float4*)(o_part + (base*NTOK + m)*TD))[tj];
    acc.x += w*v.x; acc.y += w*v.y; acc.z += w*v.z; acc.w += w*v.w;
  }
  float inv = 1.f / denom;
  osh[mi][tj*4+0] = acc.x*inv; osh[mi][tj*4+1] = acc.y*inv;
  osh[mi][tj*4+2] = acc.z*inv; osh[mi][tj*4+3] = acc.w*inv;
  __syncthreads();
  const int j0 = tj * 8;
  float o8[8] = {};
#pragma unroll
  for (int t = 0; t < TD; t++){
    float ov = osh[mi][t];
#pragma unroll
    for (int jj = 0; jj < 8; jj++) o8[jj] += ov * w2[t*2*TD + j0 + jj];
  }
  if (j0 < TD){
#pragma unroll
    for (int jj = 0; jj < 8; jj++)
      kb[(size_t)(bh*NTOK + m)*TD + j0 + jj] = f2bf(o8[jj]);
  } else {
#pragma unroll
    for (int jj = 0; jj < 8; jj++)
      vtb[(size_t)(bh*TD + (j0 - TD + jj))*NTOK + m] = f2bf(o8[jj]);
  }
}

// ---------------- K5: attn2 — swizzled LDS-staged K/V, fast-exp2 softmax ------------
__global__ __launch_bounds__(256, 2)
void k_attn2(const u16* __restrict__ q3, const u16* __restrict__ kb,
             const u16* __restrict__ vtb, u16* __restrict__ Wout){
  __shared__ __attribute__((aligned(16))) u16 buf[32768];   // 64KB exactly
  u16* kbs = buf;            // swizzled [256][64]: addr16 = r*64 + ((g ^ (r&7))<<3)
  u16* vts = buf + 16384;    // swizzled [64][256]: addr16 = t*256 + ((g ^ (t&31))<<3)
  const int tid = threadIdx.x, lane = tid & 63, wave = tid >> 6;
  const int bh = blockIdx.x >> 6, nt = blockIdx.x & 63;
  const int b = bh >> 3, h = bh & 7;
  const int l31 = lane & 31, hi = lane >> 5;
  const int n0 = nt * 128 + wave * 32;

  bf16x8 bq[4];
#pragma unroll
  for (int ks = 0; ks < 4; ks++)
    bq[ks] = ld8(q3 + (size_t)(b*NSEQ + n0 + l31)*CD + h*TD + ks*16 + hi*8);

  {
    const u16* ksrc = kb + (size_t)bh*NTOK*TD;
#pragma unroll
    for (int it = 0; it < 8; it++){
      int idx = it*256 + tid;
      int r = idx >> 3, g = idx & 7;
      int4 v; __builtin_memcpy(&v, ksrc + r*64 + g*8, 16);
      __builtin_memcpy(kbs + r*64 + ((g ^ (r & 7)) << 3), &v, 16);
    }
    const u16* vsrc = vtb + (size_t)bh*TD*NTOK;
#pragma unroll
    for (int it = 0; it < 8; it++){
      int idx = it*256 + tid;
      int t = idx >> 5, g = idx & 31;
      int4 v; __builtin_memcpy(&v, vsrc + t*256 + g*8, 16);
      __builtin_memcpy(vts + t*256 + ((g ^ (t & 31)) << 3), &v, 16);
    }
  }
  __syncthreads();

  f32x16 p[8] = {};
  __builtin_amdgcn_s_setprio(1);
#pragma unroll
  for (int kt = 0; kt < 8; kt++){
#pragma unroll
    for (int ks = 0; ks < 4; ks++){
      int r = kt*32 + l31, g = ks*2 + hi;
      bf16x8 ak = ld8(kbs + r*64 + ((g ^ (r & 7)) << 3));
      p[kt] = mfma32(ak, bq[ks], p[kt]);
    }
  }
  __builtin_amdgcn_s_setprio(0);

  float mx0 = -1e30f, mx1 = -1e30f, mx2 = -1e30f, mx3 = -1e30f;
#pragma unroll
  for (int kt = 0; kt < 8; kt++){
#pragma unroll
    for (int r = 0; r < 16; r += 4){
      mx0 = fmaxf(mx0, p[kt][r+0]); mx1 = fmaxf(mx1, p[kt][r+1]);
      mx2 = fmaxf(mx2, p[kt][r+2]); mx3 = fmaxf(mx3, p[kt][r+3]);
    }
  }
  float m = fmaxf(fmaxf(mx0, mx1), fmaxf(mx2, mx3));
  m = fmaxf(m, __shfl_xor(m, 32, 64));
  float s0 = 0.f, s1 = 0.f, s2 = 0.f, s3 = 0.f;
#pragma unroll
  for (int kt = 0; kt < 8; kt++){
#pragma unroll
    for (int r = 0; r < 16; r += 4){
      float e0 = fexp2(p[kt][r+0] - m); p[kt][r+0] = e0; s0 += e0;
      float e1 = fexp2(p[kt][r+1] - m); p[kt][r+1] = e1; s1 += e1;
      float e2 = fexp2(p[kt][r+2] - m); p[kt][r+2] = e2; s2 += e2;
      float e3 = fexp2(p[kt][r+3] - m); p[kt][r+3] = e3; s3 += e3;
    }
  }
  float rs = (s0 + s1) + (s2 + s3);
  rs += __shfl_xor(rs, 32, 64);
  const float inv = 1.f / rs;

  f32x16 o0 = {}, o1 = {};
#pragma unroll
  for (int kt = 0; kt < 8; kt++){
    u32 w[8], x[8];
#pragma unroll
    for (int j = 0; j < 8; j++){
      u32 lo = f2bf(p[kt][2*j]);
      u32 hh = f2bf(p[kt][2*j + 1]);
      w[j] = lo | (hh << 16);
    }
#pragma unroll
    for (int j = 0; j < 8; j++) x[j] = __shfl_xor(w[j], 32, 64);
    __builtin_amdgcn_s_setprio(1);
#pragma unroll
    for (int c = 0; c < 2; c++){
      u32 arr[4];
      arr[0] = hi ? x[4*c + 2] : w[4*c + 0];
      arr[1] = hi ? x[4*c + 3] : w[4*c + 1];
      arr[2] = hi ? w[4*c + 2] : x[4*c + 0];
      arr[3] = hi ? w[4*c + 3] : x[4*c + 1];
      bf16x8 pb; __builtin_memcpy(&pb, arr, 16);
      int g = kt*4 + c*2 + hi;
      bf16x8 av0 = ld8(vts + l31*256        + ((g ^ l31) << 3));
      bf16x8 av1 = ld8(vts + (l31+32)*256   + ((g ^ l31) << 3));
      o0 = mfma32(av0, pb, o0);
      o1 = mfma32(av1, pb, o1);
    }
    __builtin_amdgcn_s_setprio(0);
  }

  __syncthreads();
  u16 (*osh)[32][68] = (u16 (*)[32][68])buf;   // 4 x 32 x 68 = 17408 B
#pragma unroll
  for (int r = 0; r < 16; r++){
    int row = (r & 3) + 8*(r >> 2) + 4*hi;   // td within 32-block
    osh[wave][l31][row]      = f2bf(o0[r] * inv);
    osh[wave][l31][32 + row] = f2bf(o1[r] * inv);
  }
  const u16* src = &osh[wave][l31][hi*32];
  int4 v0, v1, v2, v3;
  __builtin_memcpy(&v0, src,      16);
  __builtin_memcpy(&v1, src + 8,  16);
  __builtin_memcpy(&v2, src + 16, 16);
  __builtin_memcpy(&v3, src + 24, 16);
  u16* dst = Wout + (size_t)(b*NSEQ + n0 + l31)*CD + h*TD + hi*32;
  __builtin_memcpy(dst,      &v0, 16);
  __builtin_memcpy(dst + 8,  &v1, 16);
  __builtin_memcpy(dst + 16, &v2, 16);
  __builtin_memcpy(dst + 24, &v3, 16);
}

// ---------------- host ----------------
extern "C" void kernel_launch(void* const* d_in, const int* in_sizes, int n_in,
                              void* d_out, int out_size, void* d_ws, size_t ws_size,
                              hipStream_t stream){
  const float* W0     = (const float*)d_in[0];
  const float* Q      = (const float*)d_in[1];
  const float* kv1_w  = (const float*)d_in[2];
  const float* kv1_b  = (const float*)d_in[3];
  const float* qkv2_w = (const float*)d_in[4];
  const float* q3_w   = (const float*)d_in[5];
  const float* q3_b   = (const float*)d_in[6];
  const float* proj_w = (const float*)d_in[7];
  const float* proj_b = (const float*)d_in[8];
  (void)in_sizes; (void)n_in; (void)out_size; (void)ws_size;

  char* ws = (char*)d_ws;
  u16*   W0b     = (u16*)  (ws);                                  // [0,32MiB)
  u16*   kv1_ws  = (u16*)  (ws + ((size_t)32<<20));               // [32,64) -> later W_ws
  float* o_part  = (float*)(ws + ((size_t)64<<20));               // [64,96)
  float* ml_part = (float*)(ws + ((size_t)96<<20));               // [96,97)
  u16*   kv1_wt  = (u16*)  (ws + ((size_t)97<<20));               // 512 KiB
  u16*   q3_wt   = (u16*)  (ws + ((size_t)97<<20) + (1<<19));     // 512 KiB
  u16*   proj_wt = (u16*)  (ws + ((size_t)98<<20));               // 512 KiB
  u16*   Qb      = (u16*)  (ws + ((size_t)98<<20) + (1<<19));     // 256 KiB
  u16*   kb      = (u16*)  (ws + ((size_t)99<<20));               // 1 MiB
  u16*   vtb     = (u16*)  (ws + ((size_t)100<<20));              // 1 MiB; total ~101 MiB
  u16*   W_ws    = (u16*)  (ws + ((size_t)32<<20));               // alias kv1_ws
  u16*   q3s     = (u16*)  d_out;                                 // first 32MB of d_out (64MB f32)

  k_cvt_prep<<<16384, 256, 0, stream>>>(W0, W0b, kv1_w, q3_w, proj_w, Q,
                                        kv1_wt, q3_wt, proj_wt, Qb);
  k_gemm_dual<<<dim3(256,4), 256, 0, stream>>>(W0b, kv1_wt, q3_wt, kv1_b, q3_b,
                                               0.125f * LOG2E, kv1_ws, q3s);
  k_attn1<<<dim3(NB*NH, 2, NSPLIT), 256, 0, stream>>>(kv1_ws, Qb, o_part, ml_part);
  k_comb<<<NB*NH*16, 256, 0, stream>>>(o_part, ml_part, qkv2_w, kb, vtb);
  k_attn2<<<NB*NH*64, 256, 0, stream>>>(q3s, kb, vtb, W_ws);
  k_gemm_proj<<<dim3(256,4), 256, 0, stream>>>(W_ws, proj_wt, proj_b, (float*)d_out);
}

// Round 24
// 199.259 us; speedup vs baseline: 1.0075x; 1.0032x over previous
//
#include <hip/hip_runtime.h>
#include <hip/hip_bf16.h>

// GTO_Atten pipeline V24, MI355X (gfx950).
// = V23 (199.9us) + dual GEMM rebuilt as 2-phase double-buffered pipeline
// (T3/T4 minimum form): BM=128,BN=64,BK=64, dbuf 64KB LDS, counted vmcnt(8),
// raw s_barrier (loads stay in flight across barriers). gload+rule-#21 swizzle
// staging (proven). All other kernels byte-identical to V23.

#define NB 4
#define NSEQ 8192
#define CD 512
#define NH 8
#define TD 64
#define NTOK 256
#define NSPLIT 16
#define NKEYS (NSEQ / NSPLIT)   // 512 keys per split
#define LOG2E 1.44269504f

typedef unsigned short u16;
typedef unsigned int u32;
typedef __bf16 bf16x8 __attribute__((ext_vector_type(8)));
typedef float f32x4 __attribute__((ext_vector_type(4)));
typedef float f32x16 __attribute__((ext_vector_type(16)));

__device__ __forceinline__ u16 f2bf(float f){
  __hip_bfloat16 h = __float2bfloat16(f);
  u16 u; __builtin_memcpy(&u, &h, 2); return u;
}
__device__ __forceinline__ bf16x8 ld8(const u16* p){
  bf16x8 r; __builtin_memcpy(&r, p, 16); return r;
}
__device__ __forceinline__ f32x4 mfma16(bf16x8 a, bf16x8 b, f32x4 c){
  return __builtin_amdgcn_mfma_f32_16x16x32_bf16(a, b, c, 0, 0, 0);
}
__device__ __forceinline__ f32x16 mfma32(bf16x8 a, bf16x8 b, f32x16 c){
  return __builtin_amdgcn_mfma_f32_32x32x16_bf16(a, b, c, 0, 0, 0);
}
__device__ __forceinline__ float fexp2(float x){
  return __builtin_amdgcn_exp2f(x);
}
__device__ __forceinline__ void gload16(const u16* g, u16* l){
  __builtin_amdgcn_global_load_lds((const __attribute__((address_space(1))) void*)g,
                                   (__attribute__((address_space(3))) void*)l, 16, 0, 0);
}

// ---------------- K0: cvt W0 + prep weights (merged; grid 16384) --------------------
__global__ void k_cvt_prep(const float* __restrict__ W0, u16* __restrict__ W0b,
                           const float* __restrict__ kv1_w, const float* __restrict__ q3_w,
                           const float* __restrict__ proj_w, const float* __restrict__ Q,
                           u16* __restrict__ kv1_wt, u16* __restrict__ q3_wt,
                           u16* __restrict__ proj_wt, u16* __restrict__ Qb){
  size_t i = (size_t)blockIdx.x * 256 + threadIdx.x;
  float4 v = ((const float4*)W0)[i];
  u16 w[4] = { f2bf(v.x), f2bf(v.y), f2bf(v.z), f2bf(v.w) };
  __builtin_memcpy(W0b + i*4, w, 8);
  if (i < (size_t)CD*CD){
    int k = (int)i >> 9, n = (int)i & 511;
    kv1_wt [n*CD + k] = f2bf(kv1_w[i]);
    q3_wt  [n*CD + k] = f2bf(q3_w[i] * (0.125f * LOG2E));
    proj_wt[n*CD + k] = f2bf(proj_w[i]);
    if (i < NH*NTOK*TD) Qb[i] = f2bf(Q[i] * (0.125f * LOG2E));
  }
}

// ---------------- Fused dual GEMM V24: 2-phase dbuf, counted vmcnt ------------------
// Tile 128x64, BK=64. Per buffer (32KB): A[128][64] + B1[64][64] + B2[64][64].
// Wave (wave>>1,wave&1) owns 64x32 of each output. 8 gload/wave/stage ->
// vmcnt(8) waits exactly the current buffer while next stays in flight.
__global__ __launch_bounds__(256, 2)
void k_gemm_dual(const u16* __restrict__ A, const u16* __restrict__ B1t,
                 const u16* __restrict__ B2t, const float* __restrict__ bias1,
                 const float* __restrict__ bias2, float bscale2,
                 u16* __restrict__ out1, u16* __restrict__ out2){
  __shared__ __attribute__((aligned(16))) u16 buf[2 * 16384];   // 65536 B
  const int tid = threadIdx.x;
  const int lane = tid & 63, wave = tid >> 6;
  const int l15 = lane & 15, lg = lane >> 4;
  const int wm = (wave >> 1) * 64, wn = (wave & 1) * 32;
  const int bm = blockIdx.x, bn = blockIdx.y;
  const int lr = lane >> 3;                  // row within 8-row segment
  const int csw = ((lane & 7) ^ lr) * 8;     // pre-swizzled source chunk (u16)
  f32x4 acc1[4][2] = {}, acc2[4][2] = {};

  // STAGE(bi, kk): 8 vmem instr/wave. A: 16 segs (4/wave); B1,B2: 8 segs (2/wave).
#define STAGE_DUAL(bi, kk) do {                                               \
    u16* Ab_  = buf + (bi)*16384;                                             \
    u16* B1b_ = Ab_ + 8192;                                                   \
    u16* B2b_ = B1b_ + 4096;                                                  \
    _Pragma("unroll")                                                         \
    for (int i_ = 0; i_ < 4; i_++){                                           \
      int seg_ = i_*4 + wave;                                                 \
      int ch_  = seg_*8 + lr;                                                 \
      gload16(A + (size_t)(bm*128 + ch_)*CD + (kk) + csw, Ab_ + seg_*512);    \
    }                                                                         \
    _Pragma("unroll")                                                         \
    for (int i_ = 0; i_ < 2; i_++){                                           \
      int seg_ = i_*4 + wave;                                                 \
      int ch_  = seg_*8 + lr;                                                 \
      gload16(B1t + (size_t)(bn*64 + ch_)*CD + (kk) + csw, B1b_ + seg_*512);  \
      gload16(B2t + (size_t)(bn*64 + ch_)*CD + (kk) + csw, B2b_ + seg_*512);  \
    }                                                                         \
  } while(0)

  STAGE_DUAL(0, 0);                          // prologue
#pragma unroll 1
  for (int t = 0; t < 8; t++){
    const int cur = t & 1;
    if (t < 7) STAGE_DUAL(cur ^ 1, (t + 1) * 64);
    if (t < 7) asm volatile("s_waitcnt vmcnt(8)" ::: "memory");
    else       asm volatile("s_waitcnt vmcnt(0)" ::: "memory");
    __builtin_amdgcn_sched_barrier(0);
    __builtin_amdgcn_s_barrier();            // all waves: current buffer resident
    u16* Ab  = buf + cur*16384;
    u16* B1b = Ab + 8192;
    u16* B2b = B1b + 4096;
#pragma unroll
    for (int ks = 0; ks < 2; ks++){
      bf16x8 af[4], b1f[2], b2f[2];
#pragma unroll
      for (int mf = 0; mf < 4; mf++){
        int R = wm + mf*16 + l15;
        int off = R*64 + (((ks*4 + lg) ^ (R & 7)) << 3);
        af[mf] = ld8(Ab + off);
      }
#pragma unroll
      for (int nf = 0; nf < 2; nf++){
        int R = wn + nf*16 + l15;
        int off = R*64 + (((ks*4 + lg) ^ (R & 7)) << 3);
        b1f[nf] = ld8(B1b + off);
        b2f[nf] = ld8(B2b + off);
      }
#pragma unroll
      for (int mf = 0; mf < 4; mf++)
#pragma unroll
        for (int nf = 0; nf < 2; nf++){
          acc1[mf][nf] = mfma16(af[mf], b1f[nf], acc1[mf][nf]);
          acc2[mf][nf] = mfma16(af[mf], b2f[nf], acc2[mf][nf]);
        }
    }
    __builtin_amdgcn_s_barrier();            // readers done before next overwrite
  }
#undef STAGE_DUAL

  // epilogue: direct stores (proven pattern)
#pragma unroll
  for (int nf = 0; nf < 2; nf++){
    int col = bn*64 + wn + nf*16 + l15;
    float bv1 = bias1[col];
    float bv2 = bias2[col] * bscale2;
#pragma unroll
    for (int mf = 0; mf < 4; mf++){
      int row = bm*128 + wm + mf*16 + lg*4;
#pragma unroll
      for (int q = 0; q < 4; q++){
        out1[(size_t)(row + q)*CD + col] = f2bf(acc1[mf][nf][q] + bv1);
        out2[(size_t)(row + q)*CD + col] = f2bf(acc2[mf][nf][q] + bv2);
      }
    }
  }
}

// ---------------- GEMM (proj): gload_lds staging + rule-#21 swizzle (V21) -----------
__global__ __launch_bounds__(256, 2)
void k_gemm_proj(const u16* __restrict__ A, const u16* __restrict__ Bt,
                 const float* __restrict__ bias, float* __restrict__ outp){
  __shared__ __attribute__((aligned(16))) u16 smem[2 * 128 * 64];   // 32768 B
  u16* As = smem;
  u16* Bs = smem + 128*64;
  const int tid = threadIdx.x;
  const int lane = tid & 63, wave = tid >> 6;
  const int l15 = lane & 15, lg = lane >> 4;
  const int wm = (wave >> 1) * 64, wn = (wave & 1) * 64;
  const int bm = blockIdx.x, bn = blockIdx.y;
  const int lr = lane >> 3;
  const int csw = ((lane & 7) ^ lr) * 8;
  f32x4 acc[4][4] = {};

#pragma unroll 1
  for (int k0 = 0; k0 < CD; k0 += 64){
    __syncthreads();
#pragma unroll
    for (int i = 0; i < 4; i++){
      int seg = i*4 + wave;
      int ch  = seg*8 + lr;
      gload16(A  + (size_t)(bm*128 + ch)*CD + k0 + csw, As + seg*512);
      gload16(Bt + (size_t)(bn*128 + ch)*CD + k0 + csw, Bs + seg*512);
    }
    __syncthreads();
#pragma unroll
    for (int ks = 0; ks < 2; ks++){
      bf16x8 af[4], bfr[4];
#pragma unroll
      for (int mf = 0; mf < 4; mf++){
        int R = wm + mf*16 + l15;
        int off = R*64 + (((ks*4 + lg) ^ (R & 7)) << 3);
        af[mf] = ld8(As + off);
      }
#pragma unroll
      for (int nf = 0; nf < 4; nf++){
        int R = wn + nf*16 + l15;
        int off = R*64 + (((ks*4 + lg) ^ (R & 7)) << 3);
        bfr[nf] = ld8(Bs + off);
      }
#pragma unroll
      for (int mf = 0; mf < 4; mf++)
#pragma unroll
        for (int nf = 0; nf < 4; nf++)
          acc[mf][nf] = mfma16(af[mf], bfr[nf], acc[mf][nf]);
    }
  }
#pragma unroll
  for (int nf = 0; nf < 4; nf++){
    int col = bn*128 + wn + nf*16 + l15;
    float bv = bias[col];
#pragma unroll
    for (int mf = 0; mf < 4; mf++){
      int row = bm*128 + wm + mf*16 + lg*4;
#pragma unroll
      for (int q = 0; q < 4; q++)
        outp[(size_t)(row + q)*CD + col] = acc[mf][nf][q] + bv;
    }
  }
}

// ---------------- K2: attn1 — swapped-QK^T 32x32, fast-exp2; 4 waves/SIMD -----------
__global__ __launch_bounds__(256, 4)
void k_attn1(const u16* __restrict__ kv1, const u16* __restrict__ Qb,
             float* __restrict__ o_part, float* __restrict__ ml_part){
  __shared__ __attribute__((aligned(16))) u16 kvs[64][72];    // [key][td]
  __shared__ __attribute__((aligned(16))) u16 kvts[64][72];   // [td][key]
  const int tid = threadIdx.x, lane = tid & 63, wave = tid >> 6;
  const int bh = blockIdx.x, mt = blockIdx.y, s = blockIdx.z;
  const int b = bh >> 3, h = bh & 7;
  const int l31 = lane & 31, hi = lane >> 5;
  const int m0 = mt*128 + wave*32;

  bf16x8 bq[4];
#pragma unroll
  for (int ks = 0; ks < 4; ks++)
    bq[ks] = ld8(Qb + (size_t)(h*NTOK + m0 + l31)*TD + ks*16 + hi*8);

  float mrun = -1e30f, srun = 0.f;
  f32x16 o0 = {}, o1 = {};

#pragma unroll 1
  for (int c = 0; c < NKEYS/64; c++){
    const int nc = s*NKEYS + c*64;
    __syncthreads();
    {
      int r = tid >> 2, sg = tid & 3, seg = sg * 16;
      const u16* src = kv1 + (size_t)(b*NSEQ + nc + r)*CD + h*TD + seg;
      int4 v0 = *(const int4*)src;
      int4 v1 = *(const int4*)(src + 8);
      __builtin_memcpy(&kvs[r][seg],     &v0, 16);
      __builtin_memcpy(&kvs[r][seg + 8], &v1, 16);
      u32 tr[8];
      __builtin_memcpy(tr,     &v0, 16);
      __builtin_memcpy(tr + 4, &v1, 16);
      u32 t1[8], t2[8];
#pragma unroll
      for (int i = 0; i < 8; i++) t1[i] = (sg & 1) ? tr[(i + 1) & 7] : tr[i];
#pragma unroll
      for (int i = 0; i < 8; i++) t2[i] = (sg & 2) ? t1[(i + 2) & 7] : t1[i];
#pragma unroll
      for (int j2 = 0; j2 < 8; j2++){
        int jj = (2*j2 + 2*sg) & 15;
        kvts[seg + jj][r]     = (u16)(t2[j2] & 0xffff);
        kvts[seg + jj + 1][r] = (u16)(t2[j2] >> 16);
      }
    }
    __syncthreads();
#pragma unroll
    for (int sub = 0; sub < 2; sub++){
      f32x16 t = {};
      __builtin_amdgcn_s_setprio(1);
#pragma unroll
      for (int ks = 0; ks < 4; ks++){
        bf16x8 ak = ld8(&kvs[sub*32 + l31][ks*16 + hi*8]);
        t = mfma32(ak, bq[ks], t);
      }
      __builtin_amdgcn_s_setprio(0);
      float c0 = fmaxf(fmaxf(t[0], t[1]),  fmaxf(t[2], t[3]));
      float c1 = fmaxf(fmaxf(t[4], t[5]),  fmaxf(t[6], t[7]));
      float c2 = fmaxf(fmaxf(t[8], t[9]),  fmaxf(t[10], t[11]));
      float c3 = fmaxf(fmaxf(t[12], t[13]), fmaxf(t[14], t[15]));
      float cm = fmaxf(fmaxf(c0, c1), fmaxf(c2, c3));
      cm = fmaxf(cm, __shfl_xor(cm, 32, 64));
      if (!__all(cm <= mrun + 11.5416f)){
        float mnew = fmaxf(mrun, cm);
        float corr = fexp2(mrun - mnew);
        srun *= corr;
#pragma unroll
        for (int r = 0; r < 16; r++){ o0[r] *= corr; o1[r] *= corr; }
        mrun = mnew;
      }
      u32 w[8], x[8];
      float ls = 0.f;
#pragma unroll
      for (int j = 0; j < 8; j++){
        float e0 = fexp2(t[2*j]     - mrun);
        float e1 = fexp2(t[2*j + 1] - mrun);
        ls += e0 + e1;
        w[j] = (u32)f2bf(e0) | ((u32)f2bf(e1) << 16);
      }
      srun += ls;
#pragma unroll
      for (int j = 0; j < 8; j++) x[j] = __shfl_xor(w[j], 32, 64);
      __builtin_amdgcn_s_setprio(1);
#pragma unroll
      for (int c2i = 0; c2i < 2; c2i++){
        u32 arr[4];
        arr[0] = hi ? x[4*c2i + 2] : w[4*c2i + 0];
        arr[1] = hi ? x[4*c2i + 3] : w[4*c2i + 1];
        arr[2] = hi ? w[4*c2i + 2] : x[4*c2i + 0];
        arr[3] = hi ? w[4*c2i + 3] : x[4*c2i + 1];
        bf16x8 pb; __builtin_memcpy(&pb, arr, 16);
        bf16x8 av0 = ld8(&kvts[l31][sub*32 + c2i*16 + hi*8]);
        bf16x8 av1 = ld8(&kvts[l31 + 32][sub*32 + c2i*16 + hi*8]);
        o0 = mfma32(av0, pb, o0);
        o1 = mfma32(av1, pb, o1);
      }
      __builtin_amdgcn_s_setprio(0);
    }
  }
  float rs = srun + __shfl_xor(srun, 32, 64);

  const size_t pbase = (size_t)(bh*NSPLIT + s);
  float* qrow = o_part + (pbase*NTOK + m0 + l31)*TD;
#pragma unroll
  for (int g = 0; g < 4; g++){
    float4 v0 = make_float4(o0[4*g+0], o0[4*g+1], o0[4*g+2], o0[4*g+3]);
    *(float4*)(qrow + 8*g + 4*hi) = v0;
    float4 v1 = make_float4(o1[4*g+0], o1[4*g+1], o1[4*g+2], o1[4*g+3]);
    *(float4*)(qrow + 32 + 8*g + 4*hi) = v1;
  }
  if (hi == 0){
    ml_part[(pbase*2)*NTOK + m0 + l31]     = mrun;
    ml_part[(pbase*2 + 1)*NTOK + m0 + l31] = rs;
  }
}

// ---------------- K3: combine partials + kv2 GEMM (log2-domain merge) ---------------
__global__ __launch_bounds__(256, 2)
void k_comb(const float* __restrict__ o_part, const float* __restrict__ ml_part,
            const float* __restrict__ qkv2_w, u16* __restrict__ kb, u16* __restrict__ vtb){
  __shared__ float w2[TD*2*TD];       // 32KB
  __shared__ float osh[16][68];
  const int tid = threadIdx.x;
  const int bh = blockIdx.x >> 4, mtile = blockIdx.x & 15;
  const int m0 = mtile * 16;
  for (int i = tid; i < TD*2*TD/4; i += 256) ((float4*)w2)[i] = ((const float4*)qkv2_w)[i];

  const int mi = tid >> 4, tj = tid & 15;
  const int m = m0 + mi;
  float M = -1e30f;
#pragma unroll
  for (int s = 0; s < NSPLIT; s++)
    M = fmaxf(M, ml_part[(size_t)((bh*NSPLIT + s)*2)*NTOK + m]);
  float4 acc = make_float4(0.f,0.f,0.f,0.f);
  float denom = 0.f;
#pragma unroll 1
  for (int s = 0; s < NSPLIT; s++){
    size_t base = (size_t)(bh*NSPLIT + s);
    float w = fexp2(ml_part[(base*2)*NTOK + m] - M);
    denom += ml_part[(base*2 + 1)*NTOK + m] * w;
    float4 v = ((const float4*)(o_part + (base*NTOK + m)*TD))[tj];
    acc.x += w*v.x; acc.y += w*v.y; acc.z += w*v.z; acc.w += w*v.w;
  }
  float inv = 1.f / denom;
  osh[mi][tj*4+0] = acc.x*inv; osh[mi][tj*4+1] = acc.y*inv;
  osh[mi][tj*4+2] = acc.z*inv; osh[mi][tj*4+3] = acc.w*inv;
  __syncthreads();
  const int j0 = tj * 8;
  float o8[8] = {};
#pragma unroll
  for (int t = 0; t < TD; t++){
    float ov = osh[mi][t];
#pragma unroll
    for (int jj = 0; jj < 8; jj++) o8[jj] += ov * w2[t*2*TD + j0 + jj];
  }
  if (j0 < TD){
#pragma unroll
    for (int jj = 0; jj < 8; jj++)
      kb[(size_t)(bh*NTOK + m)*TD + j0 + jj] = f2bf(o8[jj]);
  } else {
#pragma unroll
    for (int jj = 0; jj < 8; jj++)
      vtb[(size_t)(bh*TD + (j0 - TD + jj))*NTOK + m] = f2bf(o8[jj]);
  }
}

// ---------------- K5: attn2 — swizzled LDS-staged K/V, fast-exp2 softmax ------------
__global__ __launch_bounds__(256, 2)
void k_attn2(const u16* __restrict__ q3, const u16* __restrict__ kb,
             const u16* __restrict__ vtb, u16* __restrict__ Wout){
  __shared__ __attribute__((aligned(16))) u16 buf[32768];   // 64KB exactly
  u16* kbs = buf;            // swizzled [256][64]: addr16 = r*64 + ((g ^ (r&7))<<3)
  u16* vts = buf + 16384;    // swizzled [64][256]: addr16 = t*256 + ((g ^ (t&31))<<3)
  const int tid = threadIdx.x, lane = tid & 63, wave = tid >> 6;
  const int bh = blockIdx.x >> 6, nt = blockIdx.x & 63;
  const int b = bh >> 3, h = bh & 7;
  const int l31 = lane & 31, hi = lane >> 5;
  const int n0 = nt * 128 + wave * 32;

  bf16x8 bq[4];
#pragma unroll
  for (int ks = 0; ks < 4; ks++)
    bq[ks] = ld8(q3 + (size_t)(b*NSEQ + n0 + l31)*CD + h*TD + ks*16 + hi*8);

  {
    const u16* ksrc = kb + (size_t)bh*NTOK*TD;
#pragma unroll
    for (int it = 0; it < 8; it++){
      int idx = it*256 + tid;
      int r = idx >> 3, g = idx & 7;
      int4 v; __builtin_memcpy(&v, ksrc + r*64 + g*8, 16);
      __builtin_memcpy(kbs + r*64 + ((g ^ (r & 7)) << 3), &v, 16);
    }
    const u16* vsrc = vtb + (size_t)bh*TD*NTOK;
#pragma unroll
    for (int it = 0; it < 8; it++){
      int idx = it*256 + tid;
      int t = idx >> 5, g = idx & 31;
      int4 v; __builtin_memcpy(&v, vsrc + t*256 + g*8, 16);
      __builtin_memcpy(vts + t*256 + ((g ^ (t & 31)) << 3), &v, 16);
    }
  }
  __syncthreads();

  f32x16 p[8] = {};
  __builtin_amdgcn_s_setprio(1);
#pragma unroll
  for (int kt = 0; kt < 8; kt++){
#pragma unroll
    for (int ks = 0; ks < 4; ks++){
      int r = kt*32 + l31, g = ks*2 + hi;
      bf16x8 ak = ld8(kbs + r*64 + ((g ^ (r & 7)) << 3));
      p[kt] = mfma32(ak, bq[ks], p[kt]);
    }
  }
  __builtin_amdgcn_s_setprio(0);

  float mx0 = -1e30f, mx1 = -1e30f, mx2 = -1e30f, mx3 = -1e30f;
#pragma unroll
  for (int kt = 0; kt < 8; kt++){
#pragma unroll
    for (int r = 0; r < 16; r += 4){
      mx0 = fmaxf(mx0, p[kt][r+0]); mx1 = fmaxf(mx1, p[kt][r+1]);
      mx2 = fmaxf(mx2, p[kt][r+2]); mx3 = fmaxf(mx3, p[kt][r+3]);
    }
  }
  float m = fmaxf(fmaxf(mx0, mx1), fmaxf(mx2, mx3));
  m = fmaxf(m, __shfl_xor(m, 32, 64));
  float s0 = 0.f, s1 = 0.f, s2 = 0.f, s3 = 0.f;
#pragma unroll
  for (int kt = 0; kt < 8; kt++){
#pragma unroll
    for (int r = 0; r < 16; r += 4){
      float e0 = fexp2(p[kt][r+0] - m); p[kt][r+0] = e0; s0 += e0;
      float e1 = fexp2(p[kt][r+1] - m); p[kt][r+1] = e1; s1 += e1;
      float e2 = fexp2(p[kt][r+2] - m); p[kt][r+2] = e2; s2 += e2;
      float e3 = fexp2(p[kt][r+3] - m); p[kt][r+3] = e3; s3 += e3;
    }
  }
  float rs = (s0 + s1) + (s2 + s3);
  rs += __shfl_xor(rs, 32, 64);
  const float inv = 1.f / rs;

  f32x16 o0 = {}, o1 = {};
#pragma unroll
  for (int kt = 0; kt < 8; kt++){
    u32 w[8], x[8];
#pragma unroll
    for (int j = 0; j < 8; j++){
      u32 lo = f2bf(p[kt][2*j]);
      u32 hh = f2bf(p[kt][2*j + 1]);
      w[j] = lo | (hh << 16);
    }
#pragma unroll
    for (int j = 0; j < 8; j++) x[j] = __shfl_xor(w[j], 32, 64);
    __builtin_amdgcn_s_setprio(1);
#pragma unroll
    for (int c = 0; c < 2; c++){
      u32 arr[4];
      arr[0] = hi ? x[4*c + 2] : w[4*c + 0];
      arr[1] = hi ? x[4*c + 3] : w[4*c + 1];
      arr[2] = hi ? w[4*c + 2] : x[4*c + 0];
      arr[3] = hi ? w[4*c + 3] : x[4*c + 1];
      bf16x8 pb; __builtin_memcpy(&pb, arr, 16);
      int g = kt*4 + c*2 + hi;
      bf16x8 av0 = ld8(vts + l31*256        + ((g ^ l31) << 3));
      bf16x8 av1 = ld8(vts + (l31+32)*256   + ((g ^ l31) << 3));
      o0 = mfma32(av0, pb, o0);
      o1 = mfma32(av1, pb, o1);
    }
    __builtin_amdgcn_s_setprio(0);
  }

  __syncthreads();
  u16 (*osh)[32][68] = (u16 (*)[32][68])buf;   // 4 x 32 x 68 = 17408 B
#pragma unroll
  for (int r = 0; r < 16; r++){
    int row = (r & 3) + 8*(r >> 2) + 4*hi;   // td within 32-block
    osh[wave][l31][row]      = f2bf(o0[r] * inv);
    osh[wave][l31][32 + row] = f2bf(o1[r] * inv);
  }
  const u16* src = &osh[wave][l31][hi*32];
  int4 v0, v1, v2, v3;
  __builtin_memcpy(&v0, src,      16);
  __builtin_memcpy(&v1, src + 8,  16);
  __builtin_memcpy(&v2, src + 16, 16);
  __builtin_memcpy(&v3, src + 24, 16);
  u16* dst = Wout + (size_t)(b*NSEQ + n0 + l31)*CD + h*TD + hi*32;
  __builtin_memcpy(dst,      &v0, 16);
  __builtin_memcpy(dst + 8,  &v1, 16);
  __builtin_memcpy(dst + 16, &v2, 16);
  __builtin_memcpy(dst + 24, &v3, 16);
}

// ---------------- host ----------------
extern "C" void kernel_launch(void* const* d_in, const int* in_sizes, int n_in,
                              void* d_out, int out_size, void* d_ws, size_t ws_size,
                              hipStream_t stream){
  const float* W0     = (const float*)d_in[0];
  const float* Q      = (const float*)d_in[1];
  const float* kv1_w  = (const float*)d_in[2];
  const float* kv1_b  = (const float*)d_in[3];
  const float* qkv2_w = (const float*)d_in[4];
  const float* q3_w   = (const float*)d_in[5];
  const float* q3_b   = (const float*)d_in[6];
  const float* proj_w = (const float*)d_in[7];
  const float* proj_b = (const float*)d_in[8];
  (void)in_sizes; (void)n_in; (void)out_size; (void)ws_size;

  char* ws = (char*)d_ws;
  u16*   W0b     = (u16*)  (ws);                                  // [0,32MiB)
  u16*   kv1_ws  = (u16*)  (ws + ((size_t)32<<20));               // [32,64) -> later W_ws
  float* o_part  = (float*)(ws + ((size_t)64<<20));               // [64,96)
  float* ml_part = (float*)(ws + ((size_t)96<<20));               // [96,97)
  u16*   kv1_wt  = (u16*)  (ws + ((size_t)97<<20));               // 512 KiB
  u16*   q3_wt   = (u16*)  (ws + ((size_t)97<<20) + (1<<19));     // 512 KiB
  u16*   proj_wt = (u16*)  (ws + ((size_t)98<<20));               // 512 KiB
  u16*   Qb      = (u16*)  (ws + ((size_t)98<<20) + (1<<19));     // 256 KiB
  u16*   kb      = (u16*)  (ws + ((size_t)99<<20));               // 1 MiB
  u16*   vtb     = (u16*)  (ws + ((size_t)100<<20));              // 1 MiB; total ~101 MiB
  u16*   W_ws    = (u16*)  (ws + ((size_t)32<<20));               // alias kv1_ws
  u16*   q3s     = (u16*)  d_out;                                 // first 32MB of d_out (64MB f32)

  k_cvt_prep<<<16384, 256, 0, stream>>>(W0, W0b, kv1_w, q3_w, proj_w, Q,
                                        kv1_wt, q3_wt, proj_wt, Qb);
  k_gemm_dual<<<dim3(256, 8), 256, 0, stream>>>(W0b, kv1_wt, q3_wt, kv1_b, q3_b,
                                                0.125f * LOG2E, kv1_ws, q3s);
  k_attn1<<<dim3(NB*NH, 2, NSPLIT), 256, 0, stream>>>(kv1_ws, Qb, o_part, ml_part);
  k_comb<<<NB*NH*16, 256, 0, stream>>>(o_part, ml_part, qkv2_w, kb, vtb);
  k_attn2<<<NB*NH*64, 256, 0, stream>>>(q3s, kb, vtb, W_ws);
  k_gemm_proj<<<dim3(256,4), 256, 0, stream>>>(W_ws, proj_wt, proj_b, (float*)d_out);
}